// Round 15
// baseline (22.279 us; speedup 1.0000x reference)
//
#include <hip/hip_runtime.h>

// Problem constants (B=2, C=32, H=W=64, P=3, D=7, K=4)
constexpr float EPSF = 1e-12f;

using short8 = __attribute__((ext_vector_type(8))) short;
using f32x4  = __attribute__((ext_vector_type(4))) float;

__device__ __forceinline__ unsigned short f2bf(float f) {
    unsigned int u = __float_as_uint(f);
    u += 0x7fffu + ((u >> 16) & 1u);        // round-to-nearest-even
    return (unsigned short)(u >> 16);
}

// ---------------------------------------------------------------------------
// Monolithic kernel v10 = r13/r14 with wave specialization:
//   waves 0-5: stage kw/qw directly to LDS (no overlay, no register hold)
//   waves 6-7: wgt pipeline (B-frags per-lane from global, W-frags from L2,
//              MFMA, wgtl writes) — runs concurrently with sim staging.
// Barriers: 4 (r13 had 6). Nb/rbn/P4/P5/P6 byte-identical to r13/r14.
//
// LDS float pool (62,968 B) + chosb:
//   qw   @0     : [54 pos][36]   ft window 3x18, c-last
//   kw   @1944  : [216 pos][36]  ftm1 window 9x24, c-last
//   wgtl @9720  : [16 px][292]   wgt f32, layout [px][j*32+c]
//   Tb   @14392 : [49 uv][20]    row-collapsed box-sums
//   Nb   @15372 : [216]          per-pos sum_c ftm1^2
//   rbnb @15588 : [7][22]        1/max(||patch||,eps)
// ---------------------------------------------------------------------------
__global__ __launch_bounds__(512, 4) void agg_mono(
    const float* __restrict__ ft, const float* __restrict__ f1,
    const float* __restrict__ agg_w, const float* __restrict__ agg_bp,
    const float* __restrict__ wproj_w, const float* __restrict__ wproj_b,
    float* __restrict__ out)
{
    __shared__ __align__(16) float pool[15742];
    __shared__ int chosb[16][4];

    float* qw   = pool;                  // [54][36]
    float* kw   = pool + 1944;           // [216][36]
    float* wgtl = pool + 9720;           // [16][292]
    float* Tb   = pool + 14392;          // [49][20]
    float* Nb   = pool + 15372;          // [216]
    float* rbnb = pool + 15588;          // [7][22]

    const int t = threadIdx.x;
    const int pix0 = blockIdx.x << 4;
    const int b  = pix0 >> 12;
    const int y  = (pix0 >> 6) & 63;
    const int x0 = pix0 & 63;

    const float* ftb = ft + ((size_t)b << 17);
    const float* f1b = f1 + ((size_t)b << 17);

    // ============ Phase A (pre-B1): two concurrent wave roles ===============
    if (t < 384) {
        // ---- sim role (waves 0-5): stage kw/qw directly, b128 writes ----
        #pragma unroll
        for (int s = 0; s < 5; ++s) {
            int slot = s * 384 + t;          // 0..1919; valid < 1728 = c4*216+pos
            if (slot < 1728) {
                int c4 = slot / 216, pos = slot - c4 * 216;
                int kr = pos / 24, kc = pos - kr * 24;
                int gy = y - 4 + kr, gx = x0 - 4 + kc;
                float4 v = {0.f, 0.f, 0.f, 0.f};
                if ((unsigned)gy < 64u && (unsigned)gx < 64u) {
                    const float* p = f1b + ((size_t)(c4 << 2) << 12) + (gy << 6) + gx;
                    v.x = p[0]; v.y = p[1 << 12]; v.z = p[2 << 12]; v.w = p[3 << 12];
                }
                *reinterpret_cast<float4*>(&kw[pos * 36 + (c4 << 2)]) = v;
            }
        }
        #pragma unroll
        for (int s = 0; s < 2; ++s) {
            int slot = s * 384 + t;          // 0..767; valid < 432 = c4*54+pos
            if (slot < 432) {
                int c4 = slot / 54, pos = slot - c4 * 54;
                int qr = pos / 18, qc = pos - qr * 18;
                int gy = y - 1 + qr, gx = x0 - 1 + qc;
                float4 v = {0.f, 0.f, 0.f, 0.f};
                if ((unsigned)gy < 64u && (unsigned)gx < 64u) {
                    const float* p = ftb + ((size_t)(c4 << 2) << 12) + (gy << 6) + gx;
                    v.x = p[0]; v.y = p[1 << 12]; v.z = p[2 << 12]; v.w = p[3 << 12];
                }
                *reinterpret_cast<float4*>(&qw[pos * 36 + (c4 << 2)]) = v;
            }
        }
    } else {
        // ---- wgt role (waves 6-7): B-frags per-lane, W from L2, MFMA ----
        const int lane = t & 63;
        const int wv2 = (t >> 6) - 6;        // 0..1
        const int lr = lane & 15;            // output column = pixel
        const int lg = lane >> 4;
        // B fragments: bf0[j] = ft[ch lg*8+j](y, x0+lr); bf1[j] = f1 same.
        short8 bf0, bf1;
        {
            const float* pft = ftb + (y << 6) + x0 + lr;
            const float* pf1 = f1b + (y << 6) + x0 + lr;
            #pragma unroll
            for (int j = 0; j < 8; ++j) {
                bf0[j] = (short)f2bf(pft[(size_t)(lg * 8 + j) << 12]);
                bf1[j] = (short)f2bf(pf1[(size_t)(lg * 8 + j) << 12]);
            }
        }
        #pragma unroll 3
        for (int ti = 0; ti < 9; ++ti) {
            const int tt = wv2 + 2 * ti;     // 0..17, disjoint across the 2 waves
            const float* wrow = wproj_w + (size_t)(tt * 16 + lr) * 64 + lg * 8;
            float4 wa = *reinterpret_cast<const float4*>(wrow);
            float4 wb = *reinterpret_cast<const float4*>(wrow + 4);
            float4 wc = *reinterpret_cast<const float4*>(wrow + 32);
            float4 wd = *reinterpret_cast<const float4*>(wrow + 36);
            short8 a0, a1;
            a0[0] = (short)f2bf(wa.x); a0[1] = (short)f2bf(wa.y);
            a0[2] = (short)f2bf(wa.z); a0[3] = (short)f2bf(wa.w);
            a0[4] = (short)f2bf(wb.x); a0[5] = (short)f2bf(wb.y);
            a0[6] = (short)f2bf(wb.z); a0[7] = (short)f2bf(wb.w);
            a1[0] = (short)f2bf(wc.x); a1[1] = (short)f2bf(wc.y);
            a1[2] = (short)f2bf(wc.z); a1[3] = (short)f2bf(wc.w);
            a1[4] = (short)f2bf(wd.x); a1[5] = (short)f2bf(wd.y);
            a1[6] = (short)f2bf(wd.z); a1[7] = (short)f2bf(wd.w);
            const float4 bias = *reinterpret_cast<const float4*>(
                wproj_b + tt * 16 + lg * 4);
            f32x4 acc;
            acc[0] = bias.x; acc[1] = bias.y; acc[2] = bias.z; acc[3] = bias.w;
            acc = __builtin_amdgcn_mfma_f32_16x16x32_bf16(a0, bf0, acc, 0, 0, 0);
            acc = __builtin_amdgcn_mfma_f32_16x16x32_bf16(a1, bf1, acc, 0, 0, 0);
            #pragma unroll
            for (int qi = 0; qi < 4; ++qi) {
                int o = tt * 16 + lg * 4 + qi;       // logical o = c*9 + j
                int cc = o / 9, jj = o - cc * 9;
                wgtl[lr * 292 + jj * 32 + cc] = acc[qi];
            }
        }
    }
    __syncthreads();   // B1: kw, qw, wgtl all staged

    // ============ Phase B: Nb = sum_c ftm1^2 per window pos =================
    if (t < 216) {
        float s = 0.f;
        #pragma unroll
        for (int c4 = 0; c4 < 8; ++c4) {
            float4 v = *reinterpret_cast<const float4*>(&kw[t * 36 + (c4 << 2)]);
            s += v.x * v.x + v.y * v.y + v.z * v.z + v.w * v.w;
        }
        Nb[t] = s;
    }
    __syncthreads();   // B2

    // ============ Phase C: rbn + P4 T-dots ==================================
    if (t < 154) {
        int cyi = t / 22, cxi = t - cyi * 22;
        int kr = cyi + 1, kc = cxi + 1;
        float bn = 0.f;
        #pragma unroll
        for (int di = -1; di <= 1; ++di)
            #pragma unroll
            for (int dj = -1; dj <= 1; ++dj)
                bn += Nb[(kr + di) * 24 + kc + dj];
        rbnb[t] = 1.0f / fmaxf(sqrtf(bn), EPSF);
    }
    {
        const int g = t >> 3, c4 = t & 7;       // g 0..63
        #pragma unroll
        for (int pr = 0; pr < 2; ++pr) {
            int p = (pr << 6) + g;              // (xx,u) pair id
            if (p < 126) {
                int u = p / 18, xx = p - u * 18;
                float av[7] = {0.f, 0.f, 0.f, 0.f, 0.f, 0.f, 0.f};
                #pragma unroll
                for (int r = 0; r < 3; ++r) {
                    float4 qv = *reinterpret_cast<const float4*>(
                        &qw[(r * 18 + xx) * 36 + (c4 << 2)]);
                    #pragma unroll
                    for (int v = 0; v < 7; ++v) {
                        float4 kv = *reinterpret_cast<const float4*>(
                            &kw[((r + u) * 24 + xx + v) * 36 + (c4 << 2)]);
                        av[v] += qv.x * kv.x + qv.y * kv.y + qv.z * kv.z + qv.w * kv.w;
                    }
                }
                #pragma unroll
                for (int v = 0; v < 7; ++v) {
                    float s = av[v];
                    s += __shfl_xor(s, 1, 64);
                    s += __shfl_xor(s, 2, 64);
                    s += __shfl_xor(s, 4, 64);
                    if (c4 == 0) Tb[(u * 7 + v) * 20 + xx] = s;
                }
            }
        }
    }
    __syncthreads();   // B3

    // ============ P5: keys = box3(T)*rbn; stable top-4 per px ===============
    {
        const int lane = t & 63;
        const int wvv = t >> 6;                 // 0..7
        const int hf = lane >> 5;
        const int c = lane & 31;
        const int ppx = (wvv << 1) + hf;        // 0..15
        float s0 = 0.f, s1;
        {
            int u = c / 7, v = c - u * 7;
            int cy = y + u - 3, cx = x0 + ppx + v - 3;
            if ((unsigned)cy < 64u && (unsigned)cx < 64u) {
                float dot = Tb[c * 20 + ppx] + Tb[c * 20 + ppx + 1]
                          + Tb[c * 20 + ppx + 2];
                s0 = dot * rbnb[u * 22 + ppx + v];
            }
        }
        if (c < 17) {
            int d = c + 32;
            int u = d / 7, v = d - u * 7;
            int cy = y + u - 3, cx = x0 + ppx + v - 3;
            s1 = 0.f;
            if ((unsigned)cy < 64u && (unsigned)cx < 64u) {
                float dot = Tb[d * 20 + ppx] + Tb[d * 20 + ppx + 1]
                          + Tb[d * 20 + ppx + 2];
                s1 = dot * rbnb[u * 22 + ppx + v];
            }
        } else s1 = -3.0e38f;
        #pragma unroll
        for (int k = 0; k < 4; ++k) {
            float bs; int bi;
            if (s0 >= s1) { bs = s0; bi = c; }
            else          { bs = s1; bi = c + 32; }
            #pragma unroll
            for (int off = 16; off; off >>= 1) {   // within half-wave
                float os = __shfl_xor(bs, off, 64);
                int   oi = __shfl_xor(bi, off, 64);
                if (os > bs || (os == bs && oi < bi)) { bs = os; bi = oi; }
            }
            if (c == 0) chosb[ppx][k] = bi;
            if (bi == c)           s0 = -3.0e38f;
            else if (bi == c + 32) s1 = -3.0e38f;
        }
    }
    __syncthreads();   // B4

    // ============ P6: 128 threads, float4 gather + aggregate + store ========
    if (t < 128) {
        const int px = t & 15;
        const int c4 = t >> 4;                  // 0..7
        const int co = c4 << 2;
        const float ab = agg_bp[0];
        float awv[4];
        #pragma unroll
        for (int k = 0; k < 4; ++k) awv[k] = agg_w[k];
        int uo[4], vo[4]; bool cval[4];
        #pragma unroll
        for (int k = 0; k < 4; ++k) {
            int d = chosb[px][k];
            int u = d / 7, v = d - u * 7;
            int cy = y + u - 3, cx = x0 + px + v - 3;
            cval[k] = ((unsigned)cy < 64u) && ((unsigned)cx < 64u);
            uo[k] = u; vo[k] = v;
        }
        float4 outv = {0.f, 0.f, 0.f, 0.f};
        #pragma unroll
        for (int j = 0; j < 9; ++j) {
            int pi = j / 3, pj = j - pi * 3;
            float4 g = {ab, ab, ab, ab};
            #pragma unroll
            for (int k = 0; k < 4; ++k) {
                if (cval[k]) {
                    float4 vv = *reinterpret_cast<const float4*>(
                        &kw[((uo[k] + pi) * 24 + px + vo[k] + pj) * 36 + co]);
                    g.x += awv[k] * vv.x; g.y += awv[k] * vv.y;
                    g.z += awv[k] * vv.z; g.w += awv[k] * vv.w;
                }
            }
            float4 wg = *reinterpret_cast<const float4*>(
                &wgtl[px * 292 + j * 32 + co]);
            outv.x += wg.x * g.x; outv.y += wg.y * g.y;
            outv.z += wg.z * g.z; outv.w += wg.w * g.w;
        }
        const size_t obase = ((size_t)((b << 5) + co) << 12) + (y << 6) + x0 + px;
        out[obase]              = outv.x;
        out[obase + (1u << 12)] = outv.y;
        out[obase + (2u << 12)] = outv.z;
        out[obase + (3u << 12)] = outv.w;
    }
}

// ---------------------------------------------------------------------------
extern "C" void kernel_launch(void* const* d_in, const int* in_sizes, int n_in,
                              void* d_out, int out_size, void* d_ws, size_t ws_size,
                              hipStream_t stream)
{
    const float* feat_t   = (const float*)d_in[0];
    const float* feat_tm1 = (const float*)d_in[1];
    const float* agg_w    = (const float*)d_in[2];
    const float* agg_b    = (const float*)d_in[3];
    const float* wproj_w  = (const float*)d_in[4];
    const float* wproj_b  = (const float*)d_in[5];
    float* outp = (float*)d_out;
    (void)d_ws; (void)ws_size;

    agg_mono<<<512, 512, 0, stream>>>(feat_t, feat_tm1, agg_w, agg_b,
                                      wproj_w, wproj_b, outp);
}

// Round 16
// 21.558 us; speedup vs baseline: 1.0334x; 1.0334x over previous
//
#include <hip/hip_runtime.h>

// Problem constants (B=2, C=32, H=W=64, P=3, D=7, K=4)
constexpr float EPSF = 1e-12f;

using short8 = __attribute__((ext_vector_type(8))) short;
using f32x4  = __attribute__((ext_vector_type(4))) float;

__device__ __forceinline__ unsigned short f2bf(float f) {
    unsigned int u = __float_as_uint(f);
    u += 0x7fffu + ((u >> 16) & 1u);        // round-to-nearest-even
    return (unsigned short)(u >> 16);
}

// ---------------------------------------------------------------------------
// FINAL kernel = r13 (21.57 us, best measured). Monolithic, no workspace.
// Block = 16 output pixels, 512 threads (8 waves), 512 blocks (2/CU, whole
// grid co-resident). wgt GEMM on the matrix pipe (bf16 MFMA, fp32 accum,
// LDS-staged W); similarity/top-k path all-fp32 deterministic. Float4
// (c4,pos) staging keeps every LDS access at the wave-minimum banking.
//
// LDS float pool (65016 B) + chosb:
//   qw   @0     : 54 pos x 36   (ft window, c-last)          [born P2]
//   kw   @1944  : 216 pos x 36  (ftm1 window, c-last)        [born P2]
//   Wb   @0     : bf16[18][8][16][8] = 36864 B  (W staging)  [dead before P2]
//   wgtl @9720  : 16 px x 292   (wgt, f32)                   [born MFMA]
//   Bb   @14392 : bf16[8][16][8] (cat, b-frags)              [born P0]
//   Tb   @14904 : 49 uv x 20    (row-collapsed box-sums)
//   Nb   @15884 : 216           (sum_c ftm1^2)
//   rbnb @16100 : 7 x 22        (1/max(||patch||,eps))
// ---------------------------------------------------------------------------
__global__ __launch_bounds__(512, 4) void agg_mono(
    const float* __restrict__ ft, const float* __restrict__ f1,
    const float* __restrict__ agg_w, const float* __restrict__ agg_bp,
    const float* __restrict__ wproj_w, const float* __restrict__ wproj_b,
    float* __restrict__ out)
{
    __shared__ __align__(16) float pool[16254];
    __shared__ int chosb[16][4];

    float* qw   = pool;                  // [54][36]
    float* kw   = pool + 1944;           // [216][36]
    float* wgtl = pool + 9720;           // [16][292]
    float* Tb   = pool + 14904;          // [49][20]
    float* Nb   = pool + 15884;          // [216]
    float* rbnb = pool + 16100;          // [7][22]
    unsigned short* Wb = reinterpret_cast<unsigned short*>(pool);          // [18][8][16][8]
    unsigned short* Bb = reinterpret_cast<unsigned short*>(pool + 14392);  // [8][16][8]

    const int t = threadIdx.x;
    const int pix0 = blockIdx.x << 4;
    const int b  = pix0 >> 12;
    const int y  = (pix0 >> 6) & 63;
    const int x0 = pix0 & 63;

    const float* ftb = ft + ((size_t)b << 17);
    const float* f1b = f1 + ((size_t)b << 17);

    // ---- T14: issue window loads early into float4 registers (LDS write in
    //      P2, since kw/qw overlay Wb). Latency hides under P0b/P1. ----
    float4 stgK4[4];
    #pragma unroll
    for (int s = 0; s < 4; ++s) {
        int slot = (s << 9) + t;             // 0..2047; valid < 1728 = c4*216+pos
        if (slot < 1728) {
            int c4 = slot / 216, pos = slot - c4 * 216;
            int kr = pos / 24, kc = pos - kr * 24;
            int gy = y - 4 + kr, gx = x0 - 4 + kc;
            float4 v = {0.f, 0.f, 0.f, 0.f};
            if ((unsigned)gy < 64u && (unsigned)gx < 64u) {
                const float* p = f1b + ((size_t)(c4 << 2) << 12) + (gy << 6) + gx;
                v.x = p[0]; v.y = p[1 << 12]; v.z = p[2 << 12]; v.w = p[3 << 12];
            }
            stgK4[s] = v;
        }
    }
    float4 stgQ4 = {0.f, 0.f, 0.f, 0.f};
    if (t < 432) {                           // 432 = c4*54 + pos
        int c4 = t / 54, pos = t - c4 * 54;
        int qr = pos / 18, qc = pos - qr * 18;
        int gy = y - 1 + qr, gx = x0 - 1 + qc;
        if ((unsigned)gy < 64u && (unsigned)gx < 64u) {
            const float* p = ftb + ((size_t)(c4 << 2) << 12) + (gy << 6) + gx;
            stgQ4.x = p[0]; stgQ4.y = p[1 << 12];
            stgQ4.z = p[2 << 12]; stgQ4.w = p[3 << 12];
        }
    }

    // ---- P0: stage cat as bf16 B-fragments Bb[kg][px][8] ----
    #pragma unroll
    for (int s = 0; s < 2; ++s) {
        int idx = (s << 9) + t;              // 0..1023 = i*16 + px
        int i = idx >> 4, ppx = idx & 15;
        const float* src = (i < 32) ? ftb : f1b;
        float v = src[((size_t)(i & 31) << 12) + (y << 6) + x0 + ppx];
        Bb[(((i >> 3) << 4) + ppx) * 8 + (i & 7)] = f2bf(v);
    }

    // ---- P0b: stage W as bf16 A-tiles Wb[tt][kg][row][8] ----
    {
        const float4* w4g = reinterpret_cast<const float4*>(wproj_w);
        #pragma unroll
        for (int s = 0; s < 9; ++s) {
            int f4 = (s << 9) + t;           // 0..4607
            float4 wv = w4g[f4];
            int o = f4 >> 4, k4 = f4 & 15;
            int off = ((((o >> 4) << 3) + (k4 >> 1)) * 16 + (o & 15)) * 8
                    + ((k4 & 1) << 2);
            ushort4 bv;
            bv.x = f2bf(wv.x); bv.y = f2bf(wv.y);
            bv.z = f2bf(wv.z); bv.w = f2bf(wv.w);
            *reinterpret_cast<ushort4*>(&Wb[off]) = bv;
        }
    }
    __syncthreads();

    // ---- P1: wgt GEMM on matrix pipe. Wave w: o-tiles {w, w+8, (w+16 if w<2)}.
    //      D[row=o_local][col=px]: row=(lane>>4)*4+reg, col=lane&15 (m89). ----
    {
        const int lane = t & 63;
        const int wv8 = t >> 6;
        const int lr = lane & 15;
        const int lg = lane >> 4;
        short8 bf0 = *reinterpret_cast<const short8*>(&Bb[(lg * 16 + lr) * 8]);
        short8 bf1 = *reinterpret_cast<const short8*>(&Bb[((4 + lg) * 16 + lr) * 8]);
        #pragma unroll
        for (int ti = 0; ti < 3; ++ti) {
            if (ti == 2 && wv8 >= 2) break;
            const int tt = (ti == 0) ? wv8 : (ti == 1 ? wv8 + 8 : wv8 + 16);
            const float4 bias = *reinterpret_cast<const float4*>(
                wproj_b + tt * 16 + lg * 4);
            f32x4 acc;
            acc[0] = bias.x; acc[1] = bias.y; acc[2] = bias.z; acc[3] = bias.w;
            short8 a0 = *reinterpret_cast<const short8*>(
                &Wb[((tt * 8 + lg) * 16 + lr) * 8]);
            short8 a1 = *reinterpret_cast<const short8*>(
                &Wb[((tt * 8 + 4 + lg) * 16 + lr) * 8]);
            acc = __builtin_amdgcn_mfma_f32_16x16x32_bf16(a0, bf0, acc, 0, 0, 0);
            acc = __builtin_amdgcn_mfma_f32_16x16x32_bf16(a1, bf1, acc, 0, 0, 0);
            *reinterpret_cast<f32x4*>(&wgtl[lr * 292 + tt * 16 + lg * 4]) = acc;
        }
    }
    __syncthreads();   // Wb dead -> kw/qw writes may begin

    // ---- P2: write staged windows as ds_write_b128 (wave-minimum banking) ----
    #pragma unroll
    for (int s = 0; s < 4; ++s) {
        int slot = (s << 9) + t;
        if (slot < 1728) {
            int c4 = slot / 216, pos = slot - c4 * 216;
            *reinterpret_cast<float4*>(&kw[pos * 36 + (c4 << 2)]) = stgK4[s];
        }
    }
    if (t < 432) {
        int c4 = t / 54, pos = t - c4 * 54;
        *reinterpret_cast<float4*>(&qw[pos * 36 + (c4 << 2)]) = stgQ4;
    }
    __syncthreads();

    // ---- P3: N = sum_c ftm1^2 per window pos ----
    if (t < 216) {
        float s = 0.f;
        #pragma unroll
        for (int c4 = 0; c4 < 8; ++c4) {
            float4 v = *reinterpret_cast<const float4*>(&kw[t * 36 + (c4 << 2)]);
            s += v.x * v.x + v.y * v.y + v.z * v.z + v.w * v.w;
        }
        Nb[t] = s;
    }
    __syncthreads();
    if (t < 154) {
        int cyi = t / 22, cxi = t - cyi * 22;
        int kr = cyi + 1, kc = cxi + 1;
        float bn = 0.f;
        #pragma unroll
        for (int di = -1; di <= 1; ++di)
            #pragma unroll
            for (int dj = -1; dj <= 1; ++dj)
                bn += Nb[(kr + di) * 24 + kc + dj];
        rbnb[t] = 1.0f / fmaxf(sqrtf(bn), EPSF);
    }

    // ---- P4: T[uv][xx] = sum_r S(r,xx,uv). 8-lane c-groups, shfl reduce. ----
    {
        const int g = t >> 3, c4 = t & 7;       // g 0..63
        #pragma unroll
        for (int pr = 0; pr < 2; ++pr) {
            int p = (pr << 6) + g;              // (xx,u) pair id
            if (p < 126) {
                int u = p / 18, xx = p - u * 18;
                float av[7] = {0.f, 0.f, 0.f, 0.f, 0.f, 0.f, 0.f};
                #pragma unroll
                for (int r = 0; r < 3; ++r) {
                    float4 qv = *reinterpret_cast<const float4*>(
                        &qw[(r * 18 + xx) * 36 + (c4 << 2)]);
                    #pragma unroll
                    for (int v = 0; v < 7; ++v) {
                        float4 kv = *reinterpret_cast<const float4*>(
                            &kw[((r + u) * 24 + xx + v) * 36 + (c4 << 2)]);
                        av[v] += qv.x * kv.x + qv.y * kv.y + qv.z * kv.z + qv.w * kv.w;
                    }
                }
                #pragma unroll
                for (int v = 0; v < 7; ++v) {
                    float s = av[v];
                    s += __shfl_xor(s, 1, 64);
                    s += __shfl_xor(s, 2, 64);
                    s += __shfl_xor(s, 4, 64);
                    if (c4 == 0) Tb[(u * 7 + v) * 20 + xx] = s;
                }
            }
        }
    }
    __syncthreads();

    // ---- P5: keys = box3(T)*rbn (0 if center OOB); stable top-4 per px ----
    {
        const int lane = t & 63;
        const int wvv = t >> 6;                 // 0..7
        const int hf = lane >> 5;
        const int c = lane & 31;
        const int ppx = (wvv << 1) + hf;        // 0..15
        float s0 = 0.f, s1;
        {
            int u = c / 7, v = c - u * 7;
            int cy = y + u - 3, cx = x0 + ppx + v - 3;
            if ((unsigned)cy < 64u && (unsigned)cx < 64u) {
                float dot = Tb[c * 20 + ppx] + Tb[c * 20 + ppx + 1]
                          + Tb[c * 20 + ppx + 2];
                s0 = dot * rbnb[u * 22 + ppx + v];
            }
        }
        if (c < 17) {
            int d = c + 32;
            int u = d / 7, v = d - u * 7;
            int cy = y + u - 3, cx = x0 + ppx + v - 3;
            s1 = 0.f;
            if ((unsigned)cy < 64u && (unsigned)cx < 64u) {
                float dot = Tb[d * 20 + ppx] + Tb[d * 20 + ppx + 1]
                          + Tb[d * 20 + ppx + 2];
                s1 = dot * rbnb[u * 22 + ppx + v];
            }
        } else s1 = -3.0e38f;
        #pragma unroll
        for (int k = 0; k < 4; ++k) {
            float bs; int bi;
            if (s0 >= s1) { bs = s0; bi = c; }
            else          { bs = s1; bi = c + 32; }
            #pragma unroll
            for (int off = 16; off; off >>= 1) {   // within half-wave
                float os = __shfl_xor(bs, off, 64);
                int   oi = __shfl_xor(bi, off, 64);
                if (os > bs || (os == bs && oi < bi)) { bs = os; bi = oi; }
            }
            if (c == 0) chosb[ppx][k] = bi;
            if (bi == c)           s0 = -3.0e38f;
            else if (bi == c + 32) s1 = -3.0e38f;
        }
    }
    __syncthreads();

    // ---- P6: gather top-4 patches from kw, aggregate, multiply wgt, store.
    //      Thread (px = t&15, c = t>>4). ----
    {
        const int px = t & 15;
        const int c  = t >> 4;                  // 0..31 = channel
        const float ab = agg_bp[0];
        float awv[4];
        #pragma unroll
        for (int k = 0; k < 4; ++k) awv[k] = agg_w[k];
        int uo[4], vo[4]; bool cval[4];
        #pragma unroll
        for (int k = 0; k < 4; ++k) {
            int d = chosb[px][k];
            int u = d / 7, v = d - u * 7;
            int cy = y + u - 3, cx = x0 + px + v - 3;
            cval[k] = ((unsigned)cy < 64u) && ((unsigned)cx < 64u);
            uo[k] = u; vo[k] = v;
        }
        float outv = 0.f;
        #pragma unroll
        for (int j = 0; j < 9; ++j) {
            int pi = j / 3, pj = j - pi * 3;
            float gacc = ab;
            #pragma unroll
            for (int k = 0; k < 4; ++k) {
                float vv = cval[k]
                    ? kw[((uo[k] + pi) * 24 + px + vo[k] + pj) * 36 + c] : 0.f;
                gacc += awv[k] * vv;
            }
            outv += wgtl[px * 292 + c * 9 + j] * gacc;
        }
        out[((size_t)((b << 5) + c) << 12) + (y << 6) + x0 + px] = outv;
    }
}

// ---------------------------------------------------------------------------
extern "C" void kernel_launch(void* const* d_in, const int* in_sizes, int n_in,
                              void* d_out, int out_size, void* d_ws, size_t ws_size,
                              hipStream_t stream)
{
    const float* feat_t   = (const float*)d_in[0];
    const float* feat_tm1 = (const float*)d_in[1];
    const float* agg_w    = (const float*)d_in[2];
    const float* agg_b    = (const float*)d_in[3];
    const float* wproj_w  = (const float*)d_in[4];
    const float* wproj_b  = (const float*)d_in[5];
    float* outp = (float*)d_out;
    (void)d_ws; (void)ws_size;

    agg_mono<<<512, 512, 0, stream>>>(feat_t, feat_tm1, agg_w, agg_b,
                                      wproj_w, wproj_b, outp);
}